// Round 7
// baseline (956.701 us; speedup 1.0000x reference)
//
#include <hip/hip_runtime.h>
#include <hip/hip_bf16.h>
#include <math.h>

#define B_SZ 4
#define T_LEN 8192
#define C_IN 7
#define NPATCH 1023
#define DIM 512
#define NH 8
#define HD 64
#define NLAYERS 4
#define MLP_HID 2048
#define M_ROWS (B_SZ * NPATCH)   // 4092
#define LN_EPS 1e-5f

typedef __attribute__((ext_vector_type(8))) short short8;
typedef __attribute__((ext_vector_type(4))) float float4v;

static __device__ __forceinline__ unsigned short f2bf(float f) {
  __hip_bfloat16 h = __float2bfloat16(f);
  return *reinterpret_cast<unsigned short*>(&h);
}
static __device__ __forceinline__ float bf2f(unsigned short u) {
  return __uint_as_float(((unsigned)u) << 16);
}

// ---------------------------------------------------------------------------
// Patch embedding (fp32 — keeps emb output exact).
// ---------------------------------------------------------------------------
__global__ __launch_bounds__(128) void embed_kernel(
    const float* __restrict__ x, const float* __restrict__ Wemb,
    const float* __restrict__ bemb, float* __restrict__ emb_out,
    float* __restrict__ h) {
  int row = blockIdx.x;
  int b = row / NPATCH, i = row - b * NPATCH;
  __shared__ float patch[112];
  int tid = threadIdx.x;
  if (tid < 112) {
    int c = tid >> 4, p = tid & 15;
    patch[tid] = x[((size_t)b * T_LEN + (size_t)i * 8 + p) * C_IN + c];
  }
  __syncthreads();
  for (int d = tid; d < DIM; d += 128) {
    float acc = bemb[d];
    #pragma unroll 4
    for (int k = 0; k < 112; ++k) acc = fmaf(patch[k], Wemb[k * DIM + d], acc);
    size_t off = (size_t)row * DIM + d;
    emb_out[off] = acc;
    h[off] = acc;
  }
}

// ---------------------------------------------------------------------------
// LayerNorm, 4 rows/block. S=2: first reduce h += P0 + P1 (split-K partials,
// bias already folded), write h back, then normalize. BF: bf16 vs fp32 out.
// ---------------------------------------------------------------------------
template <bool BF, int S>
__global__ __launch_bounds__(256) void ln_kernel(
    float* __restrict__ hbuf, const float* __restrict__ P,
    const float* __restrict__ g, const float* __restrict__ bb,
    void* __restrict__ outv, int M) {
  int row = blockIdx.x * 4 + (threadIdx.x >> 6);
  if (row >= M) return;
  int lane = threadIdx.x & 63;
  float* xr = hbuf + (size_t)row * DIM;
  float v[8];
  float s = 0.f;
  #pragma unroll
  for (int k = 0; k < 8; ++k) {
    int d = lane + 64 * k;
    float t = xr[d];
    if (S == 2) {
      size_t off = (size_t)row * DIM + d;
      t += P[off] + P[(size_t)M * DIM + off];
      xr[d] = t;                       // updated residual stream
    }
    v[k] = t; s += t;
  }
  #pragma unroll
  for (int off = 32; off; off >>= 1) s += __shfl_down(s, off);
  s = __shfl(s, 0);
  float mu = s * (1.f / DIM);
  float q = 0.f;
  #pragma unroll
  for (int k = 0; k < 8; ++k) { float d = v[k] - mu; q = fmaf(d, d, q); }
  #pragma unroll
  for (int off = 32; off; off >>= 1) q += __shfl_down(q, off);
  q = __shfl(q, 0);
  float rstd = rsqrtf(q * (1.f / DIM) + LN_EPS);
  #pragma unroll
  for (int k = 0; k < 8; ++k) {
    int d = lane + 64 * k;
    float r = (v[k] - mu) * rstd * g[d] + bb[d];
    if (BF)
      ((unsigned short*)outv)[(size_t)row * DIM + d] = f2bf(r);
    else
      ((float*)outv)[(size_t)row * DIM + d] = r;
  }
}

// ---------------------------------------------------------------------------
// Weight convert + transpose: W[K][N] fp32 -> Wt[N][K] bf16 (per layer z).
// ---------------------------------------------------------------------------
__global__ __launch_bounds__(256) void wcvt_kernel(
    const float* __restrict__ W, unsigned short* __restrict__ Wt, int K, int N) {
  __shared__ float tile[32][33];
  int n0 = blockIdx.x * 32, k0 = blockIdx.y * 32, L = blockIdx.z;
  const float* Ws = W + (size_t)L * K * N;
  unsigned short* Wd = Wt + (size_t)L * K * N;
  int tx = threadIdx.x & 31, ty = threadIdx.x >> 5;
  #pragma unroll
  for (int i = 0; i < 4; ++i)
    tile[ty + i * 8][tx] = Ws[(size_t)(k0 + ty + i * 8) * N + n0 + tx];
  __syncthreads();
  #pragma unroll
  for (int i = 0; i < 4; ++i)
    Wd[(size_t)(n0 + ty + i * 8) * K + k0 + tx] = f2bf(tile[tx][ty + i * 8]);
}

// ---------------------------------------------------------------------------
// bf16 MFMA GEMM, TM x 128 tile (TM = 64 or 128), BK=32, 4 waves.
// Register-prefetch pipeline: next K-tile's global loads issue before the
// MFMA block of the current tile.
// EPI: 2 = bias+GELU -> bf16; 3 = bias -> bf16;
//      4 = split-K partial -> Cf[z*M*N + off] = acc + bias*inv_s (plain store).
// ---------------------------------------------------------------------------
template <int TM, int EPI>
__global__ __launch_bounds__(256) void mfma_gemm(
    const unsigned short* __restrict__ A, const unsigned short* __restrict__ Bt,
    const float* __restrict__ bias,
    float* __restrict__ Cf, unsigned short* __restrict__ Cb,
    int M, int N, int K, int Ks, float inv_s) {
  constexpr int NI = TM / 32;      // A frags per wave
  constexpr int CHA = TM / 64;     // A staging uint4 chunks per thread
  __shared__ __align__(16) unsigned short As[TM][40];
  __shared__ __align__(16) unsigned short Bs[128][40];
  const int bm = blockIdx.y * TM;
  const int bn = blockIdx.x * 128;
  const int tid = threadIdx.x;
  const int lane = tid & 63, wave = tid >> 6;
  const int quad = lane >> 4, l16 = lane & 15;
  const int wm = (wave & 1) * (TM / 2);
  const int wn = (wave >> 1) * 64;
  const int kb = blockIdx.z * Ks;

  float4v acc[NI][4];
  #pragma unroll
  for (int i = 0; i < NI; ++i)
    #pragma unroll
    for (int j = 0; j < 4; ++j)
      acc[i][j] = (float4v){0.f, 0.f, 0.f, 0.f};

  uint4 pa[CHA], pb[2];
  auto load_tiles = [&](int kk) {
    #pragma unroll
    for (int it = 0; it < CHA; ++it) {
      int idx = tid + it * 256;
      int row = idx >> 2, ch = (idx & 3) * 8;
      int gm = bm + row;
      pa[it] = make_uint4(0u, 0u, 0u, 0u);
      if (gm < M) pa[it] = *(const uint4*)(A + (size_t)gm * K + kk + ch);
    }
    #pragma unroll
    for (int it = 0; it < 2; ++it) {
      int idx = tid + it * 256;
      int row = idx >> 2, ch = (idx & 3) * 8;
      int gn = bn + row;   // N multiple of 128 for all our GEMMs
      pb[it] = *(const uint4*)(Bt + (size_t)gn * K + kk + ch);
    }
  };

  load_tiles(kb);
  for (int k0 = kb; k0 < kb + Ks; k0 += 32) {
    #pragma unroll
    for (int it = 0; it < CHA; ++it) {
      int idx = tid + it * 256;
      *(uint4*)&As[idx >> 2][(idx & 3) * 8] = pa[it];
    }
    #pragma unroll
    for (int it = 0; it < 2; ++it) {
      int idx = tid + it * 256;
      *(uint4*)&Bs[idx >> 2][(idx & 3) * 8] = pb[it];
    }
    __syncthreads();
    if (k0 + 32 < kb + Ks) load_tiles(k0 + 32);   // prefetch next tile
    short8 af[NI], bfr[4];
    #pragma unroll
    for (int i = 0; i < NI; ++i)
      af[i] = *(const short8*)&As[wm + i * 16 + l16][quad * 8];
    #pragma unroll
    for (int j = 0; j < 4; ++j)
      bfr[j] = *(const short8*)&Bs[wn + j * 16 + l16][quad * 8];
    #pragma unroll
    for (int i = 0; i < NI; ++i)
      #pragma unroll
      for (int j = 0; j < 4; ++j)
        acc[i][j] = __builtin_amdgcn_mfma_f32_16x16x32_bf16(
            af[i], bfr[j], acc[i][j], 0, 0, 0);
    __syncthreads();
  }

  const size_t zoff = (size_t)blockIdx.z * M * N;
  #pragma unroll
  for (int j = 0; j < 4; ++j) {
    int gn = bn + wn + j * 16 + l16;
    float bv = bias[gn] * inv_s;
    #pragma unroll
    for (int i = 0; i < NI; ++i) {
      int gm0 = bm + wm + i * 16 + quad * 4;
      #pragma unroll
      for (int r = 0; r < 4; ++r) {
        int gm = gm0 + r;
        if (gm < M) {
          float v = acc[i][j][r] + bv;
          size_t off = (size_t)gm * N + gn;
          if (EPI == 2) {
            Cb[off] = f2bf(0.5f * v * (1.f + erff(v * 0.70710678118f)));
          } else if (EPI == 3) {
            Cb[off] = f2bf(v);
          } else {
            Cf[zoff + off] = v;
          }
        }
      }
    }
  }
}

// ---------------------------------------------------------------------------
// RoPE cos/sin table: tab[i*32+j] = (cos, sin) of i * 10000^(-j/32).
// ---------------------------------------------------------------------------
__global__ __launch_bounds__(256) void rope_tab_kernel(float2* __restrict__ tab) {
  int idx = blockIdx.x * 256 + threadIdx.x;
  if (idx >= NPATCH * 32) return;
  int i = idx >> 5, j = idx & 31;
  float inv = powf(10000.0f, -(float)j * (1.0f / 32.0f));
  float sn, cs;
  sincosf((float)i * inv, &sn, &cs);
  tab[idx] = make_float2(cs, sn);
}

// ---------------------------------------------------------------------------
// RoPE in-place on bf16 qkv[row][1536] using the table; folds 0.125 into Q.
// ---------------------------------------------------------------------------
__global__ __launch_bounds__(256) void rope_kernel(
    unsigned short* __restrict__ qkvb, const float2* __restrict__ tab) {
  int row = blockIdx.x;
  int i = row % NPATCH;
  unsigned short* base = qkvb + (size_t)row * (3 * DIM);
  int tid = threadIdx.x;
  for (int p = tid; p < 512; p += 256) {
    int s = p >> 8;
    int hh = (p >> 5) & 7;
    int j = p & 31;
    float2 cssn = tab[i * 32 + j];
    int idx = s * DIM + hh * HD + j;
    float a = bf2f(base[idx]);
    float b2 = bf2f(base[idx + 32]);
    float r0 = a * cssn.x - b2 * cssn.y;
    float r1 = b2 * cssn.x + a * cssn.y;
    if (s == 0) { r0 *= 0.125f; r1 *= 0.125f; }
    base[idx]      = f2bf(r0);
    base[idx + 32] = f2bf(r1);
  }
}

// ---------------------------------------------------------------------------
// MFMA flash attention (R5, passed). Block = 4 waves = 64 queries.
// ---------------------------------------------------------------------------
#define APITCH 72

__global__ __launch_bounds__(256) void attn_kernel(
    const unsigned short* __restrict__ qkvb, unsigned short* __restrict__ o) {
  const int qt0 = blockIdx.x * 64;
  const int h = blockIdx.y;
  const int b = blockIdx.z;
  const int tid = threadIdx.x;
  const int lane = tid & 63, wave = tid >> 6;
  const int quad = lane >> 4, l16 = lane & 15;

  __shared__ __align__(16) unsigned short Qs[64][APITCH];
  __shared__ __align__(16) unsigned short Ks[64][APITCH];
  __shared__ __align__(16) unsigned short Vt[HD][APITCH];
  __shared__ __align__(16) unsigned short Ps[4][16][APITCH];

  {
    int r = tid >> 2;
    int c0 = (tid & 3) * 16;
    int qi = qt0 + r;
    uint4 a = make_uint4(0u, 0u, 0u, 0u), b2 = a;
    if (qi < NPATCH) {
      const uint4* src = (const uint4*)(qkvb + (size_t)(b * NPATCH + qi) * (3 * DIM) + h * HD + c0);
      a = src[0]; b2 = src[1];
    }
    *(uint4*)&Qs[r][c0] = a;
    *(uint4*)&Qs[r][c0 + 8] = b2;
  }
  __syncthreads();

  short8 aq0 = *(const short8*)&Qs[wave * 16 + l16][quad * 8];
  short8 aq1 = *(const short8*)&Qs[wave * 16 + l16][32 + quad * 8];

  float4v accO[4];
  #pragma unroll
  for (int j2 = 0; j2 < 4; ++j2) accO[j2] = (float4v){0.f, 0.f, 0.f, 0.f};
  float m_run[4] = {-1e30f, -1e30f, -1e30f, -1e30f};
  float l_run[4] = {0.f, 0.f, 0.f, 0.f};

  for (int j0 = 0; j0 < NPATCH; j0 += 64) {
    {
      int r = tid >> 2;
      int c0 = (tid & 3) * 16;
      int j = j0 + r;
      uint4 k0 = make_uint4(0u, 0u, 0u, 0u), k1 = k0, v0 = k0, v1 = k0;
      if (j < NPATCH) {
        const unsigned short* baseb = qkvb + (size_t)(b * NPATCH + j) * (3 * DIM) + h * HD;
        k0 = *(const uint4*)(baseb + DIM + c0);
        k1 = *(const uint4*)(baseb + DIM + c0 + 8);
        v0 = *(const uint4*)(baseb + 2 * DIM + c0);
        v1 = *(const uint4*)(baseb + 2 * DIM + c0 + 8);
      }
      *(uint4*)&Ks[r][c0] = k0;
      *(uint4*)&Ks[r][c0 + 8] = k1;
      unsigned short vs[16];
      *(uint4*)&vs[0] = v0;
      *(uint4*)&vs[8] = v1;
      #pragma unroll
      for (int u = 0; u < 16; ++u) Vt[c0 + u][r] = vs[u];
    }
    __syncthreads();

    float4v s[4];
    #pragma unroll
    for (int j = 0; j < 4; ++j) {
      s[j] = (float4v){0.f, 0.f, 0.f, 0.f};
      short8 bk0 = *(const short8*)&Ks[j * 16 + l16][quad * 8];
      short8 bk1 = *(const short8*)&Ks[j * 16 + l16][32 + quad * 8];
      s[j] = __builtin_amdgcn_mfma_f32_16x16x32_bf16(aq0, bk0, s[j], 0, 0, 0);
      s[j] = __builtin_amdgcn_mfma_f32_16x16x32_bf16(aq1, bk1, s[j], 0, 0, 0);
    }

    float mx[4], al[4], ts[4];
    #pragma unroll
    for (int r = 0; r < 4; ++r)
      mx[r] = fmaxf(fmaxf(s[0][r], s[1][r]), fmaxf(s[2][r], s[3][r]));
    #pragma unroll
    for (int mask = 1; mask < 16; mask <<= 1)
      #pragma unroll
      for (int r = 0; r < 4; ++r)
        mx[r] = fmaxf(mx[r], __shfl_xor(mx[r], mask));
    #pragma unroll
    for (int r = 0; r < 4; ++r) {
      float mnew = fmaxf(m_run[r], mx[r]);
      al[r] = __expf(m_run[r] - mnew);
      m_run[r] = mnew;
      ts[r] = 0.f;
    }
    #pragma unroll
    for (int j = 0; j < 4; ++j) {
      bool valid = (j0 + j * 16 + l16) < NPATCH;
      #pragma unroll
      for (int r = 0; r < 4; ++r) {
        float p = valid ? __expf(s[j][r] - m_run[r]) : 0.f;
        ts[r] += p;
        Ps[wave][quad * 4 + r][j * 16 + l16] = f2bf(p);
      }
    }
    #pragma unroll
    for (int mask = 1; mask < 16; mask <<= 1)
      #pragma unroll
      for (int r = 0; r < 4; ++r)
        ts[r] += __shfl_xor(ts[r], mask);
    #pragma unroll
    for (int r = 0; r < 4; ++r) l_run[r] = l_run[r] * al[r] + ts[r];
    #pragma unroll
    for (int j2 = 0; j2 < 4; ++j2)
      #pragma unroll
      for (int r = 0; r < 4; ++r)
        accO[j2][r] *= al[r];

    short8 pa0 = *(const short8*)&Ps[wave][l16][quad * 8];
    short8 pa1 = *(const short8*)&Ps[wave][l16][32 + quad * 8];
    #pragma unroll
    for (int j2 = 0; j2 < 4; ++j2) {
      short8 v0 = *(const short8*)&Vt[j2 * 16 + l16][quad * 8];
      short8 v1 = *(const short8*)&Vt[j2 * 16 + l16][32 + quad * 8];
      accO[j2] = __builtin_amdgcn_mfma_f32_16x16x32_bf16(pa0, v0, accO[j2], 0, 0, 0);
      accO[j2] = __builtin_amdgcn_mfma_f32_16x16x32_bf16(pa1, v1, accO[j2], 0, 0, 0);
    }
    __syncthreads();
  }

  #pragma unroll
  for (int r = 0; r < 4; ++r) {
    int qi = qt0 + wave * 16 + quad * 4 + r;
    if (qi < NPATCH) {
      float inv = 1.f / l_run[r];
      size_t off = (size_t)(b * NPATCH + qi) * DIM + h * HD + l16;
      #pragma unroll
      for (int j2 = 0; j2 < 4; ++j2)
        o[off + j2 * 16] = f2bf(accO[j2][r] * inv);
    }
  }
}

// ---------------------------------------------------------------------------
extern "C" void kernel_launch(void* const* d_in, const int* in_sizes, int n_in,
                              void* d_out, int out_size, void* d_ws, size_t ws_size,
                              hipStream_t stream) {
  const float* x      = (const float*)d_in[0];
  const float* W_emb  = (const float*)d_in[1];
  const float* b_emb  = (const float*)d_in[2];
  const float* ln1_g  = (const float*)d_in[3];
  const float* ln1_b  = (const float*)d_in[4];
  const float* W_qkv  = (const float*)d_in[5];
  const float* b_qkv  = (const float*)d_in[6];
  const float* W_proj = (const float*)d_in[7];
  const float* b_proj = (const float*)d_in[8];
  const float* ln2_g  = (const float*)d_in[9];
  const float* ln2_b  = (const float*)d_in[10];
  const float* W_mlp1 = (const float*)d_in[11];
  const float* b_mlp1 = (const float*)d_in[12];
  const float* W_mlp2 = (const float*)d_in[13];
  const float* b_mlp2 = (const float*)d_in[14];
  const float* lnf_g  = (const float*)d_in[15];
  const float* lnf_b  = (const float*)d_in[16];
  float* out = (float*)d_out;

  // workspace: h 8.4M | qkvb/midbf 16.8M | ybf/obf 4.2M | Wt 25.2M |
  //            rtab 0.26M | P (2 x M x 512 fp32) 16.8M  -> ~71.7M
  float* h              = (float*)d_ws;
  unsigned short* qkvb  = (unsigned short*)(h + (size_t)M_ROWS * DIM);
  unsigned short* midbf = qkvb;   // alias: qkvb dead after attn
  unsigned short* ybf   = qkvb + (size_t)M_ROWS * MLP_HID;
  unsigned short* obf   = ybf;    // alias: ybf dead after its GEMM
  unsigned short* wqkv_t  = ybf + (size_t)M_ROWS * DIM;
  unsigned short* wproj_t = wqkv_t  + (size_t)NLAYERS * DIM * 3 * DIM;
  unsigned short* wmlp1_t = wproj_t + (size_t)NLAYERS * DIM * DIM;
  unsigned short* wmlp2_t = wmlp1_t + (size_t)NLAYERS * DIM * MLP_HID;
  float2* rtab = (float2*)(wmlp2_t + (size_t)NLAYERS * MLP_HID * DIM);
  float* Pbuf  = (float*)(rtab + (size_t)NPATCH * 32);

  wcvt_kernel<<<dim3(3 * DIM / 32, DIM / 32, NLAYERS), 256, 0, stream>>>(W_qkv,  wqkv_t,  DIM, 3 * DIM);
  wcvt_kernel<<<dim3(DIM / 32, DIM / 32, NLAYERS),     256, 0, stream>>>(W_proj, wproj_t, DIM, DIM);
  wcvt_kernel<<<dim3(MLP_HID / 32, DIM / 32, NLAYERS), 256, 0, stream>>>(W_mlp1, wmlp1_t, DIM, MLP_HID);
  wcvt_kernel<<<dim3(DIM / 32, MLP_HID / 32, NLAYERS), 256, 0, stream>>>(W_mlp2, wmlp2_t, MLP_HID, DIM);
  rope_tab_kernel<<<(NPATCH * 32 + 255) / 256, 256, 0, stream>>>(rtab);

  embed_kernel<<<M_ROWS, 128, 0, stream>>>(x, W_emb, b_emb, out, h);

  const int MT64  = (M_ROWS + 63) / 64;    // 64
  const int MT128 = (M_ROWS + 127) / 128;  // 32
  const int LNG = (M_ROWS + 3) / 4;        // 1023
  for (int L = 0; L < NLAYERS; ++L) {
    if (L == 0)
      ln_kernel<true, 0><<<LNG, 256, 0, stream>>>(h, nullptr, ln1_g, ln1_b, ybf, M_ROWS);
    else
      ln_kernel<true, 2><<<LNG, 256, 0, stream>>>(h, Pbuf, ln1_g + L * DIM, ln1_b + L * DIM, ybf, M_ROWS);
    mfma_gemm<64, 3><<<dim3(3 * DIM / 128, MT64), 256, 0, stream>>>(
        ybf, wqkv_t + (size_t)L * DIM * 3 * DIM, b_qkv + L * 3 * DIM,
        nullptr, qkvb, M_ROWS, 3 * DIM, DIM, DIM, 1.f);
    rope_kernel<<<M_ROWS, 256, 0, stream>>>(qkvb, rtab);
    attn_kernel<<<dim3((NPATCH + 63) / 64, NH, B_SZ), 256, 0, stream>>>(qkvb, obf);
    // proj split-K=2 -> partials Pbuf (512 blocks)
    mfma_gemm<64, 4><<<dim3(DIM / 128, MT64, 2), 256, 0, stream>>>(
        obf, wproj_t + (size_t)L * DIM * DIM, b_proj + L * DIM,
        Pbuf, nullptr, M_ROWS, DIM, DIM, DIM / 2, 0.5f);
    ln_kernel<true, 2><<<LNG, 256, 0, stream>>>(h, Pbuf, ln2_g + L * DIM, ln2_b + L * DIM, ybf, M_ROWS);
    mfma_gemm<128, 2><<<dim3(MLP_HID / 128, MT128), 256, 0, stream>>>(
        ybf, wmlp1_t + (size_t)L * DIM * MLP_HID, b_mlp1 + L * MLP_HID,
        nullptr, midbf, M_ROWS, MLP_HID, DIM, DIM, 1.f);
    // mlp2 split-K=2 -> partials Pbuf (512 blocks)
    mfma_gemm<64, 4><<<dim3(DIM / 128, MT64, 2), 256, 0, stream>>>(
        midbf, wmlp2_t + (size_t)L * MLP_HID * DIM, b_mlp2 + L * DIM,
        Pbuf, nullptr, M_ROWS, DIM, MLP_HID, MLP_HID / 2, 0.5f);
  }

  ln_kernel<false, 2><<<LNG, 256, 0, stream>>>(h, Pbuf, lnf_g, lnf_b, out + (size_t)M_ROWS * DIM, M_ROWS);
}